// Round 15
// baseline (168.416 us; speedup 1.0000x reference)
//
#include <hip/hip_runtime.h>
#include <math.h>

#define NPTS 65536
#define NV 6890
#define NT 432               // vertex tiles of 16 (432*16 = 6912 >= 6890)
#define NTA 440              // allocated tiles (sentinel-padded for prefetch)
#define NJ 24
#define NBINS 4096           // 12-bit Morton bins
#define VSPLIT 8             // waves per block
#define TPW (NT / VSPLIT)    // 54 tiles per wave in phase 2
#define WIN 16               // phase-1 window tiles (2 per wave)
#define PTS_PER_BLK 64
#define NBLK (NPTS / PTS_PER_BLK)   // 1024

typedef double f64x4 __attribute__((ext_vector_type(4)));

// ---------- Morton (4 bits/axis, cell = 0.5 over [-4,4]) ----------
__device__ __forceinline__ unsigned mspread(unsigned v) {
    return (v & 1u) | ((v & 2u) << 2) | ((v & 4u) << 4) | ((v & 8u) << 6);
}
__device__ __forceinline__ unsigned morton12(float x, float y, float z) {
    int qx = (int)floorf((x + 4.0f) * 2.0f); qx = qx < 0 ? 0 : (qx > 15 ? 15 : qx);
    int qy = (int)floorf((y + 4.0f) * 2.0f); qy = qy < 0 ? 0 : (qy > 15 ? 15 : qy);
    int qz = (int)floorf((z + 4.0f) * 2.0f); qz = qz < 0 ? 0 : (qz > 15 ? 15 : qz);
    return mspread((unsigned)qx) | (mspread((unsigned)qy) << 1) | (mspread((unsigned)qz) << 2);
}

// ---------- fused binning kernels (order affects speed only, never values) ----------
__global__ void hist2_k(const float* __restrict__ xyz, const float* __restrict__ verts,
                        unsigned* __restrict__ pbins, unsigned* __restrict__ prank,
                        unsigned* __restrict__ vbins, unsigned* __restrict__ vrank) {
    int i = blockIdx.x * blockDim.x + threadIdx.x;
    if (i < NPTS) {
        unsigned c = morton12(xyz[3 * i], xyz[3 * i + 1], xyz[3 * i + 2]);
        prank[i] = atomicAdd(&pbins[c], 1u);
    } else {
        int j = i - NPTS;
        if (j < NV) {
            unsigned c = morton12(verts[3 * j], verts[3 * j + 1], verts[3 * j + 2]);
            vrank[j] = atomicAdd(&vbins[c], 1u);
        }
    }
}

__global__ void prefix_k(const unsigned* __restrict__ pb, const unsigned* __restrict__ vb,
                         unsigned* __restrict__ ps, unsigned* __restrict__ vs) {
    __shared__ unsigned s[NBINS];
    const int tid = threadIdx.x;                 // 1024 threads
    for (int pass = 0; pass < 2; ++pass) {
        const unsigned* in = pass ? vb : pb;
        unsigned* outp = pass ? vs : ps;
        for (int j = tid; j < NBINS; j += 1024) s[j] = in[j];
        __syncthreads();
        for (int off = 1; off < NBINS; off <<= 1) {
            unsigned v[4];
            #pragma unroll
            for (int q = 0; q < 4; ++q) {
                int j = tid + q * 1024;
                v[q] = (j >= off) ? s[j - off] : 0u;
            }
            __syncthreads();
            #pragma unroll
            for (int q = 0; q < 4; ++q) s[tid + q * 1024] += v[q];
            __syncthreads();
        }
        for (int j = tid; j < NBINS; j += 1024) outp[j + 1] = s[j];  // exclusive
        if (tid == 0) outp[0] = 0;
        __syncthreads();
    }
}

__global__ void scatter2_k(const float* __restrict__ xyz, const float* __restrict__ verts,
                           const unsigned* __restrict__ pstart, const unsigned* __restrict__ prank,
                           const unsigned* __restrict__ vstart, const unsigned* __restrict__ vrank,
                           int* __restrict__ pord, int* __restrict__ vord) {
    int i = blockIdx.x * blockDim.x + threadIdx.x;
    if (i < NPTS) {
        unsigned c = morton12(xyz[3 * i], xyz[3 * i + 1], xyz[3 * i + 2]);
        pord[pstart[c] + prank[i]] = i;
    } else {
        int j = i - NPTS;
        if (j < NV) {
            unsigned c = morton12(verts[3 * j], verts[3 * j + 1], verts[3 * j + 2]);
            vord[vstart[c] + vrank[j]] = j;
        }
    }
}

// ---------- B-fragment stream (sorted vertex order), r12-proven form ----------
__global__ void prep_frags_k(const float* __restrict__ verts, const int* __restrict__ vord,
                             double* __restrict__ bf) {
    int e = blockIdx.x * blockDim.x + threadIdx.x;
    if (e >= NTA * 64) return;
    int l = e & 63;
    int t = e >> 6;
    int pos = t * 16 + (l & 15);
    int k = l >> 4;
    double val;
    if (pos < NV) {
        int j = vord[pos];
        if (k < 3) {
            val = (double)verts[3 * j + k];
        } else {
            double x = (double)verts[3 * j + 0];
            double y = (double)verts[3 * j + 1];
            double z = (double)verts[3 * j + 2];
            val = x * x + y * y + z * z;
        }
    } else {
        val = (k == 3) ? 1e300 : 0.0;
    }
    bf[e] = val;
}

// ---------- per-tile bounding sphere (r12-proven scalar form) ----------
__global__ void tilebb_k(const float* __restrict__ verts, const int* __restrict__ vord,
                         float4* __restrict__ tbb) {
    int t = blockIdx.x * blockDim.x + threadIdx.x;
    if (t >= NTA) return;
    if (t * 16 >= NV) { tbb[t] = make_float4(1e30f, 1e30f, 1e30f, 0.0f); return; }
    float mnx = 1e30f, mny = 1e30f, mnz = 1e30f;
    float mxx = -1e30f, mxy = -1e30f, mxz = -1e30f;
    for (int c = 0; c < 16; ++c) {
        int pos = t * 16 + c;
        if (pos >= NV) break;
        int j = vord[pos];
        float x = verts[3 * j], y = verts[3 * j + 1], z = verts[3 * j + 2];
        mnx = fminf(mnx, x); mxx = fmaxf(mxx, x);
        mny = fminf(mny, y); mxy = fmaxf(mxy, y);
        mnz = fminf(mnz, z); mxz = fmaxf(mxz, z);
    }
    float cx = (mnx + mxx) * 0.5f, cy = (mny + mxy) * 0.5f, cz = (mnz + mxz) * 0.5f;
    float r2 = 0.0f;
    for (int c = 0; c < 16; ++c) {
        int pos = t * 16 + c;
        if (pos >= NV) break;
        int j = vord[pos];
        float dx = verts[3 * j] - cx, dy = verts[3 * j + 1] - cy, dz = verts[3 * j + 2] - cz;
        r2 = fmaxf(r2, dx * dx + dy * dy + dz * dz);
    }
    float r = sqrtf(r2) * 1.0002f + 1e-5f;   // conservative inflation
    tbb[t] = make_float4(cx, cy, cz, r);
}

// m = min(m, d with low-13 mantissa bits replaced by orv). Perturbation
// <= 2^13 ulp (~1e-12 rel) << NN gap (~1e-3): ordering-safe (rounds 6-12).
__device__ __forceinline__ void packmin(double& m, double d, unsigned orv) {
    unsigned long long u = __double_as_longlong(d);
    u = (u & ~0x1FFFULL) | (unsigned long long)orv;
    double t = __longlong_as_double(u);
    asm("v_min_f64 %0, %0, %1" : "+v"(m) : "v"(t));
}

// ---------- epilogue ----------
__device__ __forceinline__ void epilogue(int i, int bi,
                                         const float* __restrict__ xyz,
                                         const float* __restrict__ rot,
                                         const float* __restrict__ sw,
                                         const float* __restrict__ bt,
                                         float* __restrict__ out) {
    const float xf = xyz[3 * i + 0];
    const float yf = xyz[3 * i + 1];
    const float zf = xyz[3 * i + 2];

    const float* W = &sw[bi * NJ];
    float Tm[16];
    #pragma unroll
    for (int q = 0; q < 16; ++q) Tm[q] = 0.0f;
    #pragma unroll
    for (int kk = 0; kk < NJ; ++kk) {
        float w = W[kk];
        #pragma unroll
        for (int q = 0; q < 16; ++q) Tm[q] = fmaf(w, bt[16 * kk + q], Tm[q]);
    }

    float xb0 = Tm[0] * xf + Tm[1] * yf + Tm[2]  * zf + Tm[3];
    float xb1 = Tm[4] * xf + Tm[5] * yf + Tm[6]  * zf + Tm[7];
    float xb2 = Tm[8] * xf + Tm[9] * yf + Tm[10] * zf + Tm[11];

    float qr = rot[4 * i + 0];
    float qx = rot[4 * i + 1];
    float qy = rot[4 * i + 2];
    float qz = rot[4 * i + 3];
    float inv = 1.0f / sqrtf(qr * qr + qx * qx + qy * qy + qz * qz);
    qr *= inv; qx *= inv; qy *= inv; qz *= inv;

    float Rh[9];
    Rh[0] = 1.0f - 2.0f * (qy * qy + qz * qz);
    Rh[1] = 2.0f * (qx * qy - qr * qz);
    Rh[2] = 2.0f * (qx * qz + qr * qy);
    Rh[3] = 2.0f * (qx * qy + qr * qz);
    Rh[4] = 1.0f - 2.0f * (qx * qx + qz * qz);
    Rh[5] = 2.0f * (qy * qz - qr * qx);
    Rh[6] = 2.0f * (qx * qz - qr * qy);
    Rh[7] = 2.0f * (qy * qz + qr * qx);
    Rh[8] = 1.0f - 2.0f * (qx * qx + qy * qy);

    float RB[9];
    #pragma unroll
    for (int rr2 = 0; rr2 < 3; ++rr2) {
        #pragma unroll
        for (int cc = 0; cc < 3; ++cc) {
            RB[3 * rr2 + cc] = Tm[4 * rr2 + 0] * Rh[cc]
                             + Tm[4 * rr2 + 1] * Rh[3 + cc]
                             + Tm[4 * rr2 + 2] * Rh[6 + cc];
        }
    }

    out[3 * i + 0] = xb0;
    out[3 * i + 1] = xb1;
    out[3 * i + 2] = xb2;
    float* ob = out + 3 * NPTS + 9 * i;
    #pragma unroll
    for (int q = 0; q < 9; ++q) ob[q] = RB[q];
    float* ot = out + 12 * NPTS + 16 * i;
    #pragma unroll
    for (int q = 0; q < 16; ++q) ot[q] = Tm[q];
}

// ---------- main scan: phase-1 seed + phase-2 pruned-COMPUTE dense-load scan ----------
__launch_bounds__(512)
__global__ void smplnn_scan(const float* __restrict__ xyz,
                            const float* __restrict__ rot,
                            const double* __restrict__ bf,
                            const float* __restrict__ sw,
                            const float* __restrict__ bt,
                            const int* __restrict__ pord,
                            const int* __restrict__ vord,
                            const float4* __restrict__ tbb,
                            const unsigned* __restrict__ vstart,
                            float* __restrict__ out) {
    __shared__ float4 stbb[NTA];
    __shared__ double smin2[VSPLIT][PTS_PER_BLK];

    const int tid  = threadIdx.x;
    const int lane = tid & 63;
    const int wave = tid >> 6;
    const int r = lane & 15;
    const int k = lane >> 4;
    const int pbase = blockIdx.x * PTS_PER_BLK;

    // cache all tile spheres in LDS (consumed after the first barrier)
    for (int j = tid; j < NTA; j += 512) stbb[j] = tbb[j];

    // A fragments via point indirection (sorted order -> original ids)
    const int o0 = pord[pbase + r];
    const int o1 = pord[pbase + 16 + r];
    const int o2 = pord[pbase + 32 + r];
    const int o3 = pord[pbase + 48 + r];
    double a0 = (k == 3) ? 1.0 : -2.0 * (double)xyz[3 * o0 + k];
    double a1 = (k == 3) ? 1.0 : -2.0 * (double)xyz[3 * o1 + k];
    double a2 = (k == 3) ? 1.0 : -2.0 * (double)xyz[3 * o2 + k];
    double a3 = (k == 3) ? 1.0 : -2.0 * (double)xyz[3 * o3 + k];

    // own point (lane <-> block point) for bbox and ||p||^2
    const int om = pord[pbase + lane];
    const float px = xyz[3 * om], py = xyz[3 * om + 1], pz = xyz[3 * om + 2];
    const double pn = (double)px * px + (double)py * py + (double)pz * pz;

    // block bbox (wave-wide butterfly; identical in every wave)
    float bxmin = px, bxmax = px, bymin = py, bymax = py, bzmin = pz, bzmax = pz;
    #pragma unroll
    for (int s = 1; s < 64; s <<= 1) {
        bxmin = fminf(bxmin, __shfl_xor(bxmin, s));
        bxmax = fmaxf(bxmax, __shfl_xor(bxmax, s));
        bymin = fminf(bymin, __shfl_xor(bymin, s));
        bymax = fmaxf(bymax, __shfl_xor(bymax, s));
        bzmin = fminf(bzmin, __shfl_xor(bzmin, s));
        bzmax = fmaxf(bzmax, __shfl_xor(bzmax, s));
    }

    const f64x4 zero = {0.0, 0.0, 0.0, 0.0};

    // D-layout self-calibration (as rounds 4-12)
    double ar  = (k == 3) ? (double)r : 0.0;
    double one = (k == 3) ? 1.0 : 0.0;
    f64x4 drow = __builtin_amdgcn_mfma_f64_16x16x4f64(ar, one, zero, 0, 0, 0);
    f64x4 dcol = __builtin_amdgcn_mfma_f64_16x16x4f64(one, ar, zero, 0, 0, 0);
    int rowid[4];
    unsigned colb[4];
    #pragma unroll
    for (int v = 0; v < 4; ++v) { rowid[v] = (int)drow[v]; colb[v] = (unsigned)(int)dcol[v]; }

    double m0[4], m1[4], m2[4], m3[4];
    #pragma unroll
    for (int v = 0; v < 4; ++v) { m0[v] = 1e301; m1[v] = 1e301; m2[v] = 1e301; m3[v] = 1e301; }

#define PROCESS(T, B) do {                                                        \
        unsigned tb_ = ((unsigned)(T)) << 4;                                      \
        f64x4 d0 = __builtin_amdgcn_mfma_f64_16x16x4f64(a0, (B), zero, 0, 0, 0);  \
        f64x4 d1 = __builtin_amdgcn_mfma_f64_16x16x4f64(a1, (B), zero, 0, 0, 0);  \
        f64x4 d2 = __builtin_amdgcn_mfma_f64_16x16x4f64(a2, (B), zero, 0, 0, 0);  \
        f64x4 d3 = __builtin_amdgcn_mfma_f64_16x16x4f64(a3, (B), zero, 0, 0, 0);  \
        unsigned q0_ = tb_ | colb[0], q1_ = tb_ | colb[1];                        \
        unsigned q2_ = tb_ | colb[2], q3_ = tb_ | colb[3];                        \
        packmin(m0[0], d0[0], q0_); packmin(m0[1], d0[1], q1_);                   \
        packmin(m0[2], d0[2], q2_); packmin(m0[3], d0[3], q3_);                   \
        packmin(m1[0], d1[0], q0_); packmin(m1[1], d1[1], q1_);                   \
        packmin(m1[2], d1[2], q2_); packmin(m1[3], d1[3], q3_);                   \
        packmin(m2[0], d2[0], q0_); packmin(m2[1], d2[1], q1_);                   \
        packmin(m2[2], d2[2], q2_); packmin(m2[3], d2[3], q3_);                   \
        packmin(m3[0], d3[0], q0_); packmin(m3[1], d3[1], q1_);                   \
        packmin(m3[2], d3[2], q2_); packmin(m3[3], d3[3], q3_);                   \
    } while (0)

    // phase-1 window around the block's Morton position
    unsigned bc = morton12((bxmin + bxmax) * 0.5f, (bymin + bymax) * 0.5f,
                           (bzmin + bzmax) * 0.5f);
    int tw0 = ((int)vstart[bc] >> 4) - WIN / 2;
    if (tw0 < 0) tw0 = 0;
    if (tw0 > NT - WIN) tw0 = NT - WIN;
    tw0 = __builtin_amdgcn_readfirstlane(tw0);

    {
        int ta = tw0 + 2 * wave;
        double ba = bf[(size_t)ta * 64 + lane];
        double bb2 = bf[(size_t)(ta + 1) * 64 + lane];
        PROCESS(ta, ba);
        PROCESS(ta + 1, bb2);
    }

    auto publish = [&]() {
        double val = 0.0;
        #pragma unroll
        for (int f = 0; f < 4; ++f) {
            #pragma unroll
            for (int v = 0; v < 4; ++v) {
                double q = (f == 0) ? m0[v] : (f == 1) ? m1[v] : (f == 2) ? m2[v] : m3[v];
                #pragma unroll
                for (int s = 1; s < 16; s <<= 1) q = fmin(q, __shfl_xor(q, s, 16));
                if ((lane & 15) == f * 4 + v) val = q;
            }
        }
        smin2[wave][((lane & 15) >> 2) * 16 + rowid[lane & 3]] = val;
    };

    publish();
    __syncthreads();

    // block bound U = max over points of best dist^2 (score + ||p||^2), inflated
    double bp_ = smin2[0][lane];
    #pragma unroll
    for (int w = 1; w < VSPLIT; ++w) bp_ = fmin(bp_, smin2[w][lane]);
    double d2 = bp_ + pn;
    if (d2 < 0.0) d2 = 0.0;
    #pragma unroll
    for (int s = 1; s < 64; s <<= 1) d2 = fmax(d2, __shfl_xor(d2, s));
    const float sU = sqrtf((float)(d2 * 1.000002 + 1e-9)) + 1e-6f;
    __syncthreads();   // smin2 reused by final publish; stbb ready

    // phase 2: dense-load, compute-pruned exact scan of this wave's tile range
    {
        const int t0 = wave * TPW;
        const double* bp2 = bf + (size_t)t0 * 64 + lane;
        double b0 = bp2[0];
        double b1 = bp2[64];
        const int wlo = tw0, whi = tw0 + WIN;
        for (int t = t0; t < t0 + TPW; t += 2) {
            double p0 = bp2[128];              // unconditional 2-deep prefetch
            double p1 = bp2[192];
            bp2 += 128;
            float4 s0 = stbb[t];
            float4 s1 = stbb[t + 1];
            float dx0 = fmaxf(0.0f, fmaxf(s0.x - bxmax, bxmin - s0.x));
            float dy0 = fmaxf(0.0f, fmaxf(s0.y - bymax, bymin - s0.y));
            float dz0 = fmaxf(0.0f, fmaxf(s0.z - bzmax, bzmin - s0.z));
            float g0 = sqrtf(dx0 * dx0 + dy0 * dy0 + dz0 * dz0) - s0.w;
            float dx1 = fmaxf(0.0f, fmaxf(s1.x - bxmax, bxmin - s1.x));
            float dy1 = fmaxf(0.0f, fmaxf(s1.y - bymax, bymin - s1.y));
            float dz1 = fmaxf(0.0f, fmaxf(s1.z - bzmax, bzmin - s1.z));
            float g1 = sqrtf(dx1 * dx1 + dy1 * dy1 + dz1 * dz1) - s1.w;
            bool k0 = (g0 <= sU) && (t < wlo || t >= whi);
            bool k1 = (g1 <= sU) && ((t + 1) < wlo || (t + 1) >= whi);
            if (__any(k0)) PROCESS(t, b0);
            if (__any(k1)) PROCESS(t + 1, b1);
            b0 = p0;
            b1 = p1;
        }
    }

    publish();
    __syncthreads();

    if (wave != 0) return;

    double best = smin2[0][lane];
    #pragma unroll
    for (int w = 1; w < VSPLIT; ++w) best = fmin(best, smin2[w][lane]);
    const int bpos = (int)(__double_as_longlong(best) & 0x1FFFULL);  // sorted pos
    const int bi = vord[bpos];
    const int oi = pord[pbase + lane];
    epilogue(oi, bi, xyz, rot, sw, bt, out);
#undef PROCESS
}

extern "C" void kernel_launch(void* const* d_in, const int* in_sizes, int n_in,
                              void* d_out, int out_size, void* d_ws, size_t ws_size,
                              hipStream_t stream) {
    const float* xyz   = (const float*)d_in[0];
    const float* rot   = (const float*)d_in[1];
    const float* verts = (const float*)d_in[2];
    const float* sw    = (const float*)d_in[3];
    const float* bt    = (const float*)d_in[4];
    float* out = (float*)d_out;

    // workspace layout
    double*   bfrag  = (double*)d_ws;                       // NTA*64 doubles
    float4*   tbb    = (float4*)(bfrag + NTA * 64);         // NTA float4
    int*      pord   = (int*)(tbb + NTA);                   // NPTS
    int*      vord   = pord + NPTS;                         // 6912
    unsigned* prank  = (unsigned*)(vord + 6912);            // NPTS
    unsigned* vrank  = prank + NPTS;                        // 6912
    unsigned* pbins  = vrank + 6912;                        // NBINS
    unsigned* vbins  = pbins + NBINS;                       // NBINS
    unsigned* pstart = vbins + NBINS;                       // NBINS+1 (+pad)
    unsigned* vstart = pstart + NBINS + 4;                  // NBINS+1

    hipMemsetAsync(pbins, 0, 2 * NBINS * sizeof(unsigned), stream);  // pbins+vbins

    hist2_k<<<(NPTS + NV + 255) / 256, 256, 0, stream>>>(xyz, verts, pbins, prank, vbins, vrank);
    prefix_k<<<1, 1024, 0, stream>>>(pbins, vbins, pstart, vstart);
    scatter2_k<<<(NPTS + NV + 255) / 256, 256, 0, stream>>>(xyz, verts, pstart, prank,
                                                            vstart, vrank, pord, vord);
    prep_frags_k<<<(NTA * 64) / 256, 256, 0, stream>>>(verts, vord, bfrag);
    tilebb_k<<<(NTA + 63) / 64, 64, 0, stream>>>(verts, vord, tbb);

    smplnn_scan<<<NBLK, 512, 0, stream>>>(xyz, rot, bfrag, sw, bt,
                                          pord, vord, tbb, vstart, out);
}

// Round 16
// 168.106 us; speedup vs baseline: 1.0018x; 1.0018x over previous
//
#include <hip/hip_runtime.h>
#include <math.h>

#define NPTS 65536
#define NV 6890
#define NT 432               // vertex tiles of 16 (432*16 = 6912 >= 6890)
#define NTA 440              // allocated tiles (sentinel-padded for prefetch)
#define NJ 24
#define NBINS 4096           // 12-bit Morton bins
#define VSPLIT 8             // waves per block
#define TPW (NT / VSPLIT)    // 54 tiles per wave in phase 2
#define WIN 16               // phase-1 window tiles (2 per wave)
#define PTS_PER_BLK 64
#define NBLK (NPTS / PTS_PER_BLK)   // 1024

typedef double f64x4 __attribute__((ext_vector_type(4)));

// ---------- Morton (4 bits/axis, cell = 0.5 over [-4,4]) ----------
__device__ __forceinline__ unsigned mspread(unsigned v) {
    return (v & 1u) | ((v & 2u) << 2) | ((v & 4u) << 4) | ((v & 8u) << 6);
}
__device__ __forceinline__ unsigned morton12(float x, float y, float z) {
    int qx = (int)floorf((x + 4.0f) * 2.0f); qx = qx < 0 ? 0 : (qx > 15 ? 15 : qx);
    int qy = (int)floorf((y + 4.0f) * 2.0f); qy = qy < 0 ? 0 : (qy > 15 ? 15 : qy);
    int qz = (int)floorf((z + 4.0f) * 2.0f); qz = qz < 0 ? 0 : (qz > 15 ? 15 : qz);
    return mspread((unsigned)qx) | (mspread((unsigned)qy) << 1) | (mspread((unsigned)qz) << 2);
}

// ---------- fused binning kernels (order affects speed only, never values) ----------
__global__ void hist2_k(const float* __restrict__ xyz, const float* __restrict__ verts,
                        unsigned* __restrict__ pbins, unsigned* __restrict__ prank,
                        unsigned* __restrict__ vbins, unsigned* __restrict__ vrank) {
    int i = blockIdx.x * blockDim.x + threadIdx.x;
    if (i < NPTS) {
        unsigned c = morton12(xyz[3 * i], xyz[3 * i + 1], xyz[3 * i + 2]);
        prank[i] = atomicAdd(&pbins[c], 1u);
    } else {
        int j = i - NPTS;
        if (j < NV) {
            unsigned c = morton12(verts[3 * j], verts[3 * j + 1], verts[3 * j + 2]);
            vrank[j] = atomicAdd(&vbins[c], 1u);
        }
    }
}

__global__ void prefix_k(const unsigned* __restrict__ pb, const unsigned* __restrict__ vb,
                         unsigned* __restrict__ ps, unsigned* __restrict__ vs) {
    __shared__ unsigned s[NBINS];
    const int tid = threadIdx.x;                 // 1024 threads
    for (int pass = 0; pass < 2; ++pass) {
        const unsigned* in = pass ? vb : pb;
        unsigned* outp = pass ? vs : ps;
        for (int j = tid; j < NBINS; j += 1024) s[j] = in[j];
        __syncthreads();
        for (int off = 1; off < NBINS; off <<= 1) {
            unsigned v[4];
            #pragma unroll
            for (int q = 0; q < 4; ++q) {
                int j = tid + q * 1024;
                v[q] = (j >= off) ? s[j - off] : 0u;
            }
            __syncthreads();
            #pragma unroll
            for (int q = 0; q < 4; ++q) s[tid + q * 1024] += v[q];
            __syncthreads();
        }
        for (int j = tid; j < NBINS; j += 1024) outp[j + 1] = s[j];  // exclusive
        if (tid == 0) outp[0] = 0;
        __syncthreads();
    }
}

__global__ void scatter2_k(const float* __restrict__ xyz, const float* __restrict__ verts,
                           const unsigned* __restrict__ pstart, const unsigned* __restrict__ prank,
                           const unsigned* __restrict__ vstart, const unsigned* __restrict__ vrank,
                           int* __restrict__ pord, int* __restrict__ vord) {
    int i = blockIdx.x * blockDim.x + threadIdx.x;
    if (i < NPTS) {
        unsigned c = morton12(xyz[3 * i], xyz[3 * i + 1], xyz[3 * i + 2]);
        pord[pstart[c] + prank[i]] = i;
    } else {
        int j = i - NPTS;
        if (j < NV) {
            unsigned c = morton12(verts[3 * j], verts[3 * j + 1], verts[3 * j + 2]);
            vord[vstart[c] + vrank[j]] = j;
        }
    }
}

// ---------- B-fragment stream (sorted vertex order), r12-proven form ----------
__global__ void prep_frags_k(const float* __restrict__ verts, const int* __restrict__ vord,
                             double* __restrict__ bf) {
    int e = blockIdx.x * blockDim.x + threadIdx.x;
    if (e >= NTA * 64) return;
    int l = e & 63;
    int t = e >> 6;
    int pos = t * 16 + (l & 15);
    int k = l >> 4;
    double val;
    if (pos < NV) {
        int j = vord[pos];
        if (k < 3) {
            val = (double)verts[3 * j + k];
        } else {
            double x = (double)verts[3 * j + 0];
            double y = (double)verts[3 * j + 1];
            double z = (double)verts[3 * j + 2];
            val = x * x + y * y + z * z;
        }
    } else {
        val = (k == 3) ? 1e300 : 0.0;
    }
    bf[e] = val;
}

// ---------- per-tile bounding sphere (r12-proven scalar form) ----------
__global__ void tilebb_k(const float* __restrict__ verts, const int* __restrict__ vord,
                         float4* __restrict__ tbb) {
    int t = blockIdx.x * blockDim.x + threadIdx.x;
    if (t >= NTA) return;
    if (t * 16 >= NV) { tbb[t] = make_float4(1e30f, 1e30f, 1e30f, 0.0f); return; }
    float mnx = 1e30f, mny = 1e30f, mnz = 1e30f;
    float mxx = -1e30f, mxy = -1e30f, mxz = -1e30f;
    for (int c = 0; c < 16; ++c) {
        int pos = t * 16 + c;
        if (pos >= NV) break;
        int j = vord[pos];
        float x = verts[3 * j], y = verts[3 * j + 1], z = verts[3 * j + 2];
        mnx = fminf(mnx, x); mxx = fmaxf(mxx, x);
        mny = fminf(mny, y); mxy = fmaxf(mxy, y);
        mnz = fminf(mnz, z); mxz = fmaxf(mxz, z);
    }
    float cx = (mnx + mxx) * 0.5f, cy = (mny + mxy) * 0.5f, cz = (mnz + mxz) * 0.5f;
    float r2 = 0.0f;
    for (int c = 0; c < 16; ++c) {
        int pos = t * 16 + c;
        if (pos >= NV) break;
        int j = vord[pos];
        float dx = verts[3 * j] - cx, dy = verts[3 * j + 1] - cy, dz = verts[3 * j + 2] - cz;
        r2 = fmaxf(r2, dx * dx + dy * dy + dz * dz);
    }
    float r = sqrtf(r2) * 1.0002f + 1e-5f;   // conservative inflation
    tbb[t] = make_float4(cx, cy, cz, r);
}

// m = min(m, d with low-13 mantissa bits replaced by orv). Perturbation
// <= 2^13 ulp (~1e-12 rel) << NN gap (~1e-3): ordering-safe (rounds 6-12).
__device__ __forceinline__ void packmin(double& m, double d, unsigned orv) {
    unsigned long long u = __double_as_longlong(d);
    u = (u & ~0x1FFFULL) | (unsigned long long)orv;
    double t = __longlong_as_double(u);
    asm("v_min_f64 %0, %0, %1" : "+v"(m) : "v"(t));
}

// ---------- epilogue ----------
__device__ __forceinline__ void epilogue(int i, int bi,
                                         const float* __restrict__ xyz,
                                         const float* __restrict__ rot,
                                         const float* __restrict__ sw,
                                         const float* __restrict__ bt,
                                         float* __restrict__ out) {
    const float xf = xyz[3 * i + 0];
    const float yf = xyz[3 * i + 1];
    const float zf = xyz[3 * i + 2];

    const float* W = &sw[bi * NJ];
    float Tm[16];
    #pragma unroll
    for (int q = 0; q < 16; ++q) Tm[q] = 0.0f;
    #pragma unroll
    for (int kk = 0; kk < NJ; ++kk) {
        float w = W[kk];
        #pragma unroll
        for (int q = 0; q < 16; ++q) Tm[q] = fmaf(w, bt[16 * kk + q], Tm[q]);
    }

    float xb0 = Tm[0] * xf + Tm[1] * yf + Tm[2]  * zf + Tm[3];
    float xb1 = Tm[4] * xf + Tm[5] * yf + Tm[6]  * zf + Tm[7];
    float xb2 = Tm[8] * xf + Tm[9] * yf + Tm[10] * zf + Tm[11];

    float qr = rot[4 * i + 0];
    float qx = rot[4 * i + 1];
    float qy = rot[4 * i + 2];
    float qz = rot[4 * i + 3];
    float inv = 1.0f / sqrtf(qr * qr + qx * qx + qy * qy + qz * qz);
    qr *= inv; qx *= inv; qy *= inv; qz *= inv;

    float Rh[9];
    Rh[0] = 1.0f - 2.0f * (qy * qy + qz * qz);
    Rh[1] = 2.0f * (qx * qy - qr * qz);
    Rh[2] = 2.0f * (qx * qz + qr * qy);
    Rh[3] = 2.0f * (qx * qy + qr * qz);
    Rh[4] = 1.0f - 2.0f * (qx * qx + qz * qz);
    Rh[5] = 2.0f * (qy * qz - qr * qx);
    Rh[6] = 2.0f * (qx * qz - qr * qy);
    Rh[7] = 2.0f * (qy * qz + qr * qx);
    Rh[8] = 1.0f - 2.0f * (qx * qx + qy * qy);

    float RB[9];
    #pragma unroll
    for (int rr2 = 0; rr2 < 3; ++rr2) {
        #pragma unroll
        for (int cc = 0; cc < 3; ++cc) {
            RB[3 * rr2 + cc] = Tm[4 * rr2 + 0] * Rh[cc]
                             + Tm[4 * rr2 + 1] * Rh[3 + cc]
                             + Tm[4 * rr2 + 2] * Rh[6 + cc];
        }
    }

    out[3 * i + 0] = xb0;
    out[3 * i + 1] = xb1;
    out[3 * i + 2] = xb2;
    float* ob = out + 3 * NPTS + 9 * i;
    #pragma unroll
    for (int q = 0; q < 9; ++q) ob[q] = RB[q];
    float* ot = out + 12 * NPTS + 16 * i;
    #pragma unroll
    for (int q = 0; q < 16; ++q) ot[q] = Tm[q];
}

// ---------- main scan: phase-1 seed + phase-2 pruned-COMPUTE dense-load scan ----------
__launch_bounds__(512)
__global__ void smplnn_scan(const float* __restrict__ xyz,
                            const float* __restrict__ rot,
                            const double* __restrict__ bf,
                            const float* __restrict__ sw,
                            const float* __restrict__ bt,
                            const int* __restrict__ pord,
                            const int* __restrict__ vord,
                            const float4* __restrict__ tbb,
                            const unsigned* __restrict__ vstart,
                            float* __restrict__ out) {
    __shared__ float4 stbb[NTA];
    __shared__ double smin2[VSPLIT][PTS_PER_BLK];

    const int tid  = threadIdx.x;
    const int lane = tid & 63;
    const int wave = tid >> 6;
    const int r = lane & 15;
    const int k = lane >> 4;
    const int pbase = blockIdx.x * PTS_PER_BLK;

    // cache all tile spheres in LDS (consumed after the first barrier)
    for (int j = tid; j < NTA; j += 512) stbb[j] = tbb[j];

    // A fragments via point indirection (sorted order -> original ids)
    const int o0 = pord[pbase + r];
    const int o1 = pord[pbase + 16 + r];
    const int o2 = pord[pbase + 32 + r];
    const int o3 = pord[pbase + 48 + r];
    double a0 = (k == 3) ? 1.0 : -2.0 * (double)xyz[3 * o0 + k];
    double a1 = (k == 3) ? 1.0 : -2.0 * (double)xyz[3 * o1 + k];
    double a2 = (k == 3) ? 1.0 : -2.0 * (double)xyz[3 * o2 + k];
    double a3 = (k == 3) ? 1.0 : -2.0 * (double)xyz[3 * o3 + k];

    // own point (lane <-> block point) for bbox and ||p||^2
    const int om = pord[pbase + lane];
    const float px = xyz[3 * om], py = xyz[3 * om + 1], pz = xyz[3 * om + 2];
    const double pn = (double)px * px + (double)py * py + (double)pz * pz;

    // block bbox (wave-wide butterfly; identical in every wave)
    float bxmin = px, bxmax = px, bymin = py, bymax = py, bzmin = pz, bzmax = pz;
    #pragma unroll
    for (int s = 1; s < 64; s <<= 1) {
        bxmin = fminf(bxmin, __shfl_xor(bxmin, s));
        bxmax = fmaxf(bxmax, __shfl_xor(bxmax, s));
        bymin = fminf(bymin, __shfl_xor(bymin, s));
        bymax = fmaxf(bymax, __shfl_xor(bymax, s));
        bzmin = fminf(bzmin, __shfl_xor(bzmin, s));
        bzmax = fmaxf(bzmax, __shfl_xor(bzmax, s));
    }

    const f64x4 zero = {0.0, 0.0, 0.0, 0.0};

    // D-layout self-calibration (as rounds 4-12)
    double ar  = (k == 3) ? (double)r : 0.0;
    double one = (k == 3) ? 1.0 : 0.0;
    f64x4 drow = __builtin_amdgcn_mfma_f64_16x16x4f64(ar, one, zero, 0, 0, 0);
    f64x4 dcol = __builtin_amdgcn_mfma_f64_16x16x4f64(one, ar, zero, 0, 0, 0);
    int rowid[4];
    unsigned colb[4];
    #pragma unroll
    for (int v = 0; v < 4; ++v) { rowid[v] = (int)drow[v]; colb[v] = (unsigned)(int)dcol[v]; }

    double m0[4], m1[4], m2[4], m3[4];
    #pragma unroll
    for (int v = 0; v < 4; ++v) { m0[v] = 1e301; m1[v] = 1e301; m2[v] = 1e301; m3[v] = 1e301; }

#define PROCESS(T, B) do {                                                        \
        unsigned tb_ = ((unsigned)(T)) << 4;                                      \
        f64x4 d0 = __builtin_amdgcn_mfma_f64_16x16x4f64(a0, (B), zero, 0, 0, 0);  \
        f64x4 d1 = __builtin_amdgcn_mfma_f64_16x16x4f64(a1, (B), zero, 0, 0, 0);  \
        f64x4 d2 = __builtin_amdgcn_mfma_f64_16x16x4f64(a2, (B), zero, 0, 0, 0);  \
        f64x4 d3 = __builtin_amdgcn_mfma_f64_16x16x4f64(a3, (B), zero, 0, 0, 0);  \
        unsigned q0_ = tb_ | colb[0], q1_ = tb_ | colb[1];                        \
        unsigned q2_ = tb_ | colb[2], q3_ = tb_ | colb[3];                        \
        packmin(m0[0], d0[0], q0_); packmin(m0[1], d0[1], q1_);                   \
        packmin(m0[2], d0[2], q2_); packmin(m0[3], d0[3], q3_);                   \
        packmin(m1[0], d1[0], q0_); packmin(m1[1], d1[1], q1_);                   \
        packmin(m1[2], d1[2], q2_); packmin(m1[3], d1[3], q3_);                   \
        packmin(m2[0], d2[0], q0_); packmin(m2[1], d2[1], q1_);                   \
        packmin(m2[2], d2[2], q2_); packmin(m2[3], d2[3], q3_);                   \
        packmin(m3[0], d3[0], q0_); packmin(m3[1], d3[1], q1_);                   \
        packmin(m3[2], d3[2], q2_); packmin(m3[3], d3[3], q3_);                   \
    } while (0)

    // phase-1 window around the block's Morton position
    unsigned bc = morton12((bxmin + bxmax) * 0.5f, (bymin + bymax) * 0.5f,
                           (bzmin + bzmax) * 0.5f);
    int tw0 = ((int)vstart[bc] >> 4) - WIN / 2;
    if (tw0 < 0) tw0 = 0;
    if (tw0 > NT - WIN) tw0 = NT - WIN;
    tw0 = __builtin_amdgcn_readfirstlane(tw0);

    {
        int ta = tw0 + 2 * wave;
        double ba = bf[(size_t)ta * 64 + lane];
        double bb2 = bf[(size_t)(ta + 1) * 64 + lane];
        PROCESS(ta, ba);
        PROCESS(ta + 1, bb2);
    }

    auto publish = [&]() {
        double val = 0.0;
        #pragma unroll
        for (int f = 0; f < 4; ++f) {
            #pragma unroll
            for (int v = 0; v < 4; ++v) {
                double q = (f == 0) ? m0[v] : (f == 1) ? m1[v] : (f == 2) ? m2[v] : m3[v];
                #pragma unroll
                for (int s = 1; s < 16; s <<= 1) q = fmin(q, __shfl_xor(q, s, 16));
                if ((lane & 15) == f * 4 + v) val = q;
            }
        }
        smin2[wave][((lane & 15) >> 2) * 16 + rowid[lane & 3]] = val;
    };

    publish();
    __syncthreads();

    // block bound U = max over points of best dist^2 (score + ||p||^2), inflated
    double bp_ = smin2[0][lane];
    #pragma unroll
    for (int w = 1; w < VSPLIT; ++w) bp_ = fmin(bp_, smin2[w][lane]);
    double d2 = bp_ + pn;
    if (d2 < 0.0) d2 = 0.0;
    #pragma unroll
    for (int s = 1; s < 64; s <<= 1) d2 = fmax(d2, __shfl_xor(d2, s));
    const float sU = sqrtf((float)(d2 * 1.000002 + 1e-9)) + 1e-6f;
    __syncthreads();   // smin2 reused by final publish; stbb ready

    // phase 2: dense-load, compute-pruned exact scan of this wave's tile range
    {
        const int t0 = wave * TPW;
        const double* bp2 = bf + (size_t)t0 * 64 + lane;
        double b0 = bp2[0];
        double b1 = bp2[64];
        const int wlo = tw0, whi = tw0 + WIN;
        for (int t = t0; t < t0 + TPW; t += 2) {
            double p0 = bp2[128];              // unconditional 2-deep prefetch
            double p1 = bp2[192];
            bp2 += 128;
            float4 s0 = stbb[t];
            float4 s1 = stbb[t + 1];
            float dx0 = fmaxf(0.0f, fmaxf(s0.x - bxmax, bxmin - s0.x));
            float dy0 = fmaxf(0.0f, fmaxf(s0.y - bymax, bymin - s0.y));
            float dz0 = fmaxf(0.0f, fmaxf(s0.z - bzmax, bzmin - s0.z));
            float g0 = sqrtf(dx0 * dx0 + dy0 * dy0 + dz0 * dz0) - s0.w;
            float dx1 = fmaxf(0.0f, fmaxf(s1.x - bxmax, bxmin - s1.x));
            float dy1 = fmaxf(0.0f, fmaxf(s1.y - bymax, bymin - s1.y));
            float dz1 = fmaxf(0.0f, fmaxf(s1.z - bzmax, bzmin - s1.z));
            float g1 = sqrtf(dx1 * dx1 + dy1 * dy1 + dz1 * dz1) - s1.w;
            bool k0 = (g0 <= sU) && (t < wlo || t >= whi);
            bool k1 = (g1 <= sU) && ((t + 1) < wlo || (t + 1) >= whi);
            if (__any(k0)) PROCESS(t, b0);
            if (__any(k1)) PROCESS(t + 1, b1);
            b0 = p0;
            b1 = p1;
        }
    }

    publish();
    __syncthreads();

    if (wave != 0) return;

    double best = smin2[0][lane];
    #pragma unroll
    for (int w = 1; w < VSPLIT; ++w) best = fmin(best, smin2[w][lane]);
    const int bpos = (int)(__double_as_longlong(best) & 0x1FFFULL);  // sorted pos
    const int bi = vord[bpos];
    const int oi = pord[pbase + lane];
    epilogue(oi, bi, xyz, rot, sw, bt, out);
#undef PROCESS
}

extern "C" void kernel_launch(void* const* d_in, const int* in_sizes, int n_in,
                              void* d_out, int out_size, void* d_ws, size_t ws_size,
                              hipStream_t stream) {
    const float* xyz   = (const float*)d_in[0];
    const float* rot   = (const float*)d_in[1];
    const float* verts = (const float*)d_in[2];
    const float* sw    = (const float*)d_in[3];
    const float* bt    = (const float*)d_in[4];
    float* out = (float*)d_out;

    // workspace layout
    double*   bfrag  = (double*)d_ws;                       // NTA*64 doubles
    float4*   tbb    = (float4*)(bfrag + NTA * 64);         // NTA float4
    int*      pord   = (int*)(tbb + NTA);                   // NPTS
    int*      vord   = pord + NPTS;                         // 6912
    unsigned* prank  = (unsigned*)(vord + 6912);            // NPTS
    unsigned* vrank  = prank + NPTS;                        // 6912
    unsigned* pbins  = vrank + 6912;                        // NBINS
    unsigned* vbins  = pbins + NBINS;                       // NBINS
    unsigned* pstart = vbins + NBINS;                       // NBINS+1 (+pad)
    unsigned* vstart = pstart + NBINS + 4;                  // NBINS+1

    hipMemsetAsync(pbins, 0, 2 * NBINS * sizeof(unsigned), stream);  // pbins+vbins

    hist2_k<<<(NPTS + NV + 255) / 256, 256, 0, stream>>>(xyz, verts, pbins, prank, vbins, vrank);
    prefix_k<<<1, 1024, 0, stream>>>(pbins, vbins, pstart, vstart);
    scatter2_k<<<(NPTS + NV + 255) / 256, 256, 0, stream>>>(xyz, verts, pstart, prank,
                                                            vstart, vrank, pord, vord);
    prep_frags_k<<<(NTA * 64) / 256, 256, 0, stream>>>(verts, vord, bfrag);
    tilebb_k<<<(NTA + 63) / 64, 64, 0, stream>>>(verts, vord, tbb);

    smplnn_scan<<<NBLK, 512, 0, stream>>>(xyz, rot, bfrag, sw, bt,
                                          pord, vord, tbb, vstart, out);
}

// Round 17
// 135.147 us; speedup vs baseline: 1.2462x; 1.2439x over previous
//
#include <hip/hip_runtime.h>
#include <math.h>

#define NPTS 65536
#define NV 6890
#define NT 432               // vertex tiles of 16 (432*16 = 6912 >= 6890)
#define NTA 440              // allocated tiles (sentinel-padded for prefetch)
#define NJ 24
#define NBINS 4096           // 12-bit Morton bins
#define VSPLIT 8             // waves per block
#define WIN 16               // phase-1 window tiles (2 per wave)
#define PTS_PER_BLK 64
#define NBLK (NPTS / PTS_PER_BLK)   // 1024

typedef double f64x4 __attribute__((ext_vector_type(4)));

// ---------- Morton (4 bits/axis, cell = 0.5 over [-4,4]) ----------
__device__ __forceinline__ unsigned mspread(unsigned v) {
    return (v & 1u) | ((v & 2u) << 2) | ((v & 4u) << 4) | ((v & 8u) << 6);
}
__device__ __forceinline__ unsigned morton12(float x, float y, float z) {
    int qx = (int)floorf((x + 4.0f) * 2.0f); qx = qx < 0 ? 0 : (qx > 15 ? 15 : qx);
    int qy = (int)floorf((y + 4.0f) * 2.0f); qy = qy < 0 ? 0 : (qy > 15 ? 15 : qy);
    int qz = (int)floorf((z + 4.0f) * 2.0f); qz = qz < 0 ? 0 : (qz > 15 ? 15 : qz);
    return mspread((unsigned)qx) | (mspread((unsigned)qy) << 1) | (mspread((unsigned)qz) << 2);
}

// ---------- fused binning kernels (order affects speed only, never values) ----------
__global__ void hist2_k(const float* __restrict__ xyz, const float* __restrict__ verts,
                        unsigned* __restrict__ pbins, unsigned* __restrict__ prank,
                        unsigned* __restrict__ vbins, unsigned* __restrict__ vrank) {
    int i = blockIdx.x * blockDim.x + threadIdx.x;
    if (i < NPTS) {
        unsigned c = morton12(xyz[3 * i], xyz[3 * i + 1], xyz[3 * i + 2]);
        prank[i] = atomicAdd(&pbins[c], 1u);
    } else {
        int j = i - NPTS;
        if (j < NV) {
            unsigned c = morton12(verts[3 * j], verts[3 * j + 1], verts[3 * j + 2]);
            vrank[j] = atomicAdd(&vbins[c], 1u);
        }
    }
}

__global__ void prefix_k(const unsigned* __restrict__ pb, const unsigned* __restrict__ vb,
                         unsigned* __restrict__ ps, unsigned* __restrict__ vs) {
    __shared__ unsigned s[NBINS];
    const int tid = threadIdx.x;                 // 1024 threads
    for (int pass = 0; pass < 2; ++pass) {
        const unsigned* in = pass ? vb : pb;
        unsigned* outp = pass ? vs : ps;
        for (int j = tid; j < NBINS; j += 1024) s[j] = in[j];
        __syncthreads();
        for (int off = 1; off < NBINS; off <<= 1) {
            unsigned v[4];
            #pragma unroll
            for (int q = 0; q < 4; ++q) {
                int j = tid + q * 1024;
                v[q] = (j >= off) ? s[j - off] : 0u;
            }
            __syncthreads();
            #pragma unroll
            for (int q = 0; q < 4; ++q) s[tid + q * 1024] += v[q];
            __syncthreads();
        }
        for (int j = tid; j < NBINS; j += 1024) outp[j + 1] = s[j];  // exclusive
        if (tid == 0) outp[0] = 0;
        __syncthreads();
    }
}

__global__ void scatter2_k(const float* __restrict__ xyz, const float* __restrict__ verts,
                           const unsigned* __restrict__ pstart, const unsigned* __restrict__ prank,
                           const unsigned* __restrict__ vstart, const unsigned* __restrict__ vrank,
                           int* __restrict__ pord, int* __restrict__ vord) {
    int i = blockIdx.x * blockDim.x + threadIdx.x;
    if (i < NPTS) {
        unsigned c = morton12(xyz[3 * i], xyz[3 * i + 1], xyz[3 * i + 2]);
        pord[pstart[c] + prank[i]] = i;
    } else {
        int j = i - NPTS;
        if (j < NV) {
            unsigned c = morton12(verts[3 * j], verts[3 * j + 1], verts[3 * j + 2]);
            vord[vstart[c] + vrank[j]] = j;
        }
    }
}

// ---------- B-fragment stream (sorted vertex order), r12-proven form ----------
__global__ void prep_frags_k(const float* __restrict__ verts, const int* __restrict__ vord,
                             double* __restrict__ bf) {
    int e = blockIdx.x * blockDim.x + threadIdx.x;
    if (e >= NTA * 64) return;
    int l = e & 63;
    int t = e >> 6;
    int pos = t * 16 + (l & 15);
    int k = l >> 4;
    double val;
    if (pos < NV) {
        int j = vord[pos];
        if (k < 3) {
            val = (double)verts[3 * j + k];
        } else {
            double x = (double)verts[3 * j + 0];
            double y = (double)verts[3 * j + 1];
            double z = (double)verts[3 * j + 2];
            val = x * x + y * y + z * z;
        }
    } else {
        val = (k == 3) ? 1e300 : 0.0;
    }
    bf[e] = val;
}

// ---------- per-tile bounding sphere (r12-proven scalar form) ----------
__global__ void tilebb_k(const float* __restrict__ verts, const int* __restrict__ vord,
                         float4* __restrict__ tbb) {
    int t = blockIdx.x * blockDim.x + threadIdx.x;
    if (t >= NTA) return;
    if (t * 16 >= NV) { tbb[t] = make_float4(1e30f, 1e30f, 1e30f, 0.0f); return; }
    float mnx = 1e30f, mny = 1e30f, mnz = 1e30f;
    float mxx = -1e30f, mxy = -1e30f, mxz = -1e30f;
    for (int c = 0; c < 16; ++c) {
        int pos = t * 16 + c;
        if (pos >= NV) break;
        int j = vord[pos];
        float x = verts[3 * j], y = verts[3 * j + 1], z = verts[3 * j + 2];
        mnx = fminf(mnx, x); mxx = fmaxf(mxx, x);
        mny = fminf(mny, y); mxy = fmaxf(mxy, y);
        mnz = fminf(mnz, z); mxz = fmaxf(mxz, z);
    }
    float cx = (mnx + mxx) * 0.5f, cy = (mny + mxy) * 0.5f, cz = (mnz + mxz) * 0.5f;
    float r2 = 0.0f;
    for (int c = 0; c < 16; ++c) {
        int pos = t * 16 + c;
        if (pos >= NV) break;
        int j = vord[pos];
        float dx = verts[3 * j] - cx, dy = verts[3 * j + 1] - cy, dz = verts[3 * j + 2] - cz;
        r2 = fmaxf(r2, dx * dx + dy * dy + dz * dz);
    }
    float r = sqrtf(r2) * 1.0002f + 1e-5f;   // conservative inflation
    tbb[t] = make_float4(cx, cy, cz, r);
}

// m = min(m, d with low-13 mantissa bits replaced by orv). Perturbation
// <= 2^13 ulp (~1e-12 rel) << NN gap (~1e-3): ordering-safe (rounds 6-16).
__device__ __forceinline__ void packmin(double& m, double d, unsigned orv) {
    unsigned long long u = __double_as_longlong(d);
    u = (u & ~0x1FFFULL) | (unsigned long long)orv;
    double t = __longlong_as_double(u);
    asm("v_min_f64 %0, %0, %1" : "+v"(m) : "v"(t));
}

// ---------- epilogue ----------
__device__ __forceinline__ void epilogue(int i, int bi,
                                         const float* __restrict__ xyz,
                                         const float* __restrict__ rot,
                                         const float* __restrict__ sw,
                                         const float* __restrict__ bt,
                                         float* __restrict__ out) {
    const float xf = xyz[3 * i + 0];
    const float yf = xyz[3 * i + 1];
    const float zf = xyz[3 * i + 2];

    const float* W = &sw[bi * NJ];
    float Tm[16];
    #pragma unroll
    for (int q = 0; q < 16; ++q) Tm[q] = 0.0f;
    #pragma unroll
    for (int kk = 0; kk < NJ; ++kk) {
        float w = W[kk];
        #pragma unroll
        for (int q = 0; q < 16; ++q) Tm[q] = fmaf(w, bt[16 * kk + q], Tm[q]);
    }

    float xb0 = Tm[0] * xf + Tm[1] * yf + Tm[2]  * zf + Tm[3];
    float xb1 = Tm[4] * xf + Tm[5] * yf + Tm[6]  * zf + Tm[7];
    float xb2 = Tm[8] * xf + Tm[9] * yf + Tm[10] * zf + Tm[11];

    float qr = rot[4 * i + 0];
    float qx = rot[4 * i + 1];
    float qy = rot[4 * i + 2];
    float qz = rot[4 * i + 3];
    float inv = 1.0f / sqrtf(qr * qr + qx * qx + qy * qy + qz * qz);
    qr *= inv; qx *= inv; qy *= inv; qz *= inv;

    float Rh[9];
    Rh[0] = 1.0f - 2.0f * (qy * qy + qz * qz);
    Rh[1] = 2.0f * (qx * qy - qr * qz);
    Rh[2] = 2.0f * (qx * qz + qr * qy);
    Rh[3] = 2.0f * (qx * qy + qr * qz);
    Rh[4] = 1.0f - 2.0f * (qx * qx + qz * qz);
    Rh[5] = 2.0f * (qy * qz - qr * qx);
    Rh[6] = 2.0f * (qx * qz - qr * qy);
    Rh[7] = 2.0f * (qy * qz + qr * qx);
    Rh[8] = 1.0f - 2.0f * (qx * qx + qy * qy);

    float RB[9];
    #pragma unroll
    for (int rr2 = 0; rr2 < 3; ++rr2) {
        #pragma unroll
        for (int cc = 0; cc < 3; ++cc) {
            RB[3 * rr2 + cc] = Tm[4 * rr2 + 0] * Rh[cc]
                             + Tm[4 * rr2 + 1] * Rh[3 + cc]
                             + Tm[4 * rr2 + 2] * Rh[6 + cc];
        }
    }

    out[3 * i + 0] = xb0;
    out[3 * i + 1] = xb1;
    out[3 * i + 2] = xb2;
    float* ob = out + 3 * NPTS + 9 * i;
    #pragma unroll
    for (int q = 0; q < 9; ++q) ob[q] = RB[q];
    float* ot = out + 12 * NPTS + 16 * i;
    #pragma unroll
    for (int q = 0; q < 16; ++q) ot[q] = Tm[q];
}

// ---------- main scan: phase-1 seed + kept-tile list + dense list loop ----------
__launch_bounds__(512)
__global__ void smplnn_scan(const float* __restrict__ xyz,
                            const float* __restrict__ rot,
                            const double* __restrict__ bf,
                            const float* __restrict__ sw,
                            const float* __restrict__ bt,
                            const int* __restrict__ pord,
                            const int* __restrict__ vord,
                            const float4* __restrict__ tbb,
                            const unsigned* __restrict__ vstart,
                            float* __restrict__ out) {
    __shared__ float4 stbb[NTA];
    __shared__ double smin2[VSPLIT][PTS_PER_BLK];
    __shared__ unsigned short slist[448];
    __shared__ int scount;

    const int tid  = threadIdx.x;
    const int lane = tid & 63;
    const int wave = tid >> 6;
    const int r = lane & 15;
    const int k = lane >> 4;
    const int pbase = blockIdx.x * PTS_PER_BLK;

    // cache all tile spheres in LDS (consumed after the first barrier)
    for (int j = tid; j < NTA; j += 512) stbb[j] = tbb[j];
    if (tid == 0) scount = 0;

    // A fragments via point indirection (sorted order -> original ids)
    const int o0 = pord[pbase + r];
    const int o1 = pord[pbase + 16 + r];
    const int o2 = pord[pbase + 32 + r];
    const int o3 = pord[pbase + 48 + r];
    double a0 = (k == 3) ? 1.0 : -2.0 * (double)xyz[3 * o0 + k];
    double a1 = (k == 3) ? 1.0 : -2.0 * (double)xyz[3 * o1 + k];
    double a2 = (k == 3) ? 1.0 : -2.0 * (double)xyz[3 * o2 + k];
    double a3 = (k == 3) ? 1.0 : -2.0 * (double)xyz[3 * o3 + k];

    // own point (lane <-> block point) for bbox and ||p||^2
    const int om = pord[pbase + lane];
    const float px = xyz[3 * om], py = xyz[3 * om + 1], pz = xyz[3 * om + 2];
    const double pn = (double)px * px + (double)py * py + (double)pz * pz;

    // block bbox (wave-wide butterfly; identical in every wave)
    float bxmin = px, bxmax = px, bymin = py, bymax = py, bzmin = pz, bzmax = pz;
    #pragma unroll
    for (int s = 1; s < 64; s <<= 1) {
        bxmin = fminf(bxmin, __shfl_xor(bxmin, s));
        bxmax = fmaxf(bxmax, __shfl_xor(bxmax, s));
        bymin = fminf(bymin, __shfl_xor(bymin, s));
        bymax = fmaxf(bymax, __shfl_xor(bymax, s));
        bzmin = fminf(bzmin, __shfl_xor(bzmin, s));
        bzmax = fmaxf(bzmax, __shfl_xor(bzmax, s));
    }

    const f64x4 zero = {0.0, 0.0, 0.0, 0.0};

    // D-layout self-calibration (as rounds 4-16)
    double ar  = (k == 3) ? (double)r : 0.0;
    double one = (k == 3) ? 1.0 : 0.0;
    f64x4 drow = __builtin_amdgcn_mfma_f64_16x16x4f64(ar, one, zero, 0, 0, 0);
    f64x4 dcol = __builtin_amdgcn_mfma_f64_16x16x4f64(one, ar, zero, 0, 0, 0);
    int rowid[4];
    unsigned colb[4];
    #pragma unroll
    for (int v = 0; v < 4; ++v) { rowid[v] = (int)drow[v]; colb[v] = (unsigned)(int)dcol[v]; }

    double m0[4], m1[4], m2[4], m3[4];
    #pragma unroll
    for (int v = 0; v < 4; ++v) { m0[v] = 1e301; m1[v] = 1e301; m2[v] = 1e301; m3[v] = 1e301; }

#define PROCESS(T, B) do {                                                        \
        unsigned tb_ = ((unsigned)(T)) << 4;                                      \
        f64x4 d0 = __builtin_amdgcn_mfma_f64_16x16x4f64(a0, (B), zero, 0, 0, 0);  \
        f64x4 d1 = __builtin_amdgcn_mfma_f64_16x16x4f64(a1, (B), zero, 0, 0, 0);  \
        f64x4 d2 = __builtin_amdgcn_mfma_f64_16x16x4f64(a2, (B), zero, 0, 0, 0);  \
        f64x4 d3 = __builtin_amdgcn_mfma_f64_16x16x4f64(a3, (B), zero, 0, 0, 0);  \
        unsigned q0_ = tb_ | colb[0], q1_ = tb_ | colb[1];                        \
        unsigned q2_ = tb_ | colb[2], q3_ = tb_ | colb[3];                        \
        packmin(m0[0], d0[0], q0_); packmin(m0[1], d0[1], q1_);                   \
        packmin(m0[2], d0[2], q2_); packmin(m0[3], d0[3], q3_);                   \
        packmin(m1[0], d1[0], q0_); packmin(m1[1], d1[1], q1_);                   \
        packmin(m1[2], d1[2], q2_); packmin(m1[3], d1[3], q3_);                   \
        packmin(m2[0], d2[0], q0_); packmin(m2[1], d2[1], q1_);                   \
        packmin(m2[2], d2[2], q2_); packmin(m2[3], d2[3], q3_);                   \
        packmin(m3[0], d3[0], q0_); packmin(m3[1], d3[1], q1_);                   \
        packmin(m3[2], d3[2], q2_); packmin(m3[3], d3[3], q3_);                   \
    } while (0)

    // phase-1 window around the block's Morton position
    unsigned bc = morton12((bxmin + bxmax) * 0.5f, (bymin + bymax) * 0.5f,
                           (bzmin + bzmax) * 0.5f);
    int tw0 = ((int)vstart[bc] >> 4) - WIN / 2;
    if (tw0 < 0) tw0 = 0;
    if (tw0 > NT - WIN) tw0 = NT - WIN;
    tw0 = __builtin_amdgcn_readfirstlane(tw0);

    {
        int ta = tw0 + 2 * wave;
        double ba = bf[(size_t)ta * 64 + lane];
        double bb2 = bf[(size_t)(ta + 1) * 64 + lane];
        PROCESS(ta, ba);
        PROCESS(ta + 1, bb2);
    }

    auto publish = [&]() {
        double val = 0.0;
        #pragma unroll
        for (int f = 0; f < 4; ++f) {
            #pragma unroll
            for (int v = 0; v < 4; ++v) {
                double q = (f == 0) ? m0[v] : (f == 1) ? m1[v] : (f == 2) ? m2[v] : m3[v];
                #pragma unroll
                for (int s = 1; s < 16; s <<= 1) q = fmin(q, __shfl_xor(q, s, 16));
                if ((lane & 15) == f * 4 + v) val = q;
            }
        }
        smin2[wave][((lane & 15) >> 2) * 16 + rowid[lane & 3]] = val;
    };

    publish();
    __syncthreads();

    // block bound U = max over points of best dist^2 (score + ||p||^2), inflated
    double bp_ = smin2[0][lane];
    #pragma unroll
    for (int w = 1; w < VSPLIT; ++w) bp_ = fmin(bp_, smin2[w][lane]);
    double d2 = bp_ + pn;
    if (d2 < 0.0) d2 = 0.0;
    #pragma unroll
    for (int s = 1; s < 64; s <<= 1) d2 = fmax(d2, __shfl_xor(d2, s));
    const float sU = sqrtf((float)(d2 * 1.000002 + 1e-9)) + 1e-6f;
    __syncthreads();   // smin2 reuse; scount zero visible; stbb ready

    // build kept-tile list: one thread per tile (thread-parallel prune test)
    if (tid < NT) {
        const int t = tid;
        float4 s0 = stbb[t];
        float dx = fmaxf(0.0f, fmaxf(s0.x - bxmax, bxmin - s0.x));
        float dy = fmaxf(0.0f, fmaxf(s0.y - bymax, bymin - s0.y));
        float dz = fmaxf(0.0f, fmaxf(s0.z - bzmax, bzmin - s0.z));
        float gap = sqrtf(dx * dx + dy * dy + dz * dz) - s0.w;
        bool keep = (gap <= sU) && (t < tw0 || t >= tw0 + WIN);
        if (keep) {
            int p = atomicAdd(&scount, 1);
            slist[p] = (unsigned short)t;
        }
    }
    __syncthreads();

    const int M = scount;
    const int Mp = (M + VSPLIT - 1) & ~(VSPLIT - 1);
    if (tid >= M && tid < Mp) slist[tid] = NT;   // sentinel tile (harmless no-op)
    __syncthreads();

    // dense pipelined loop over kept tiles (strided across waves; order-free min)
    {
        const int nit = Mp / VSPLIT;
        if (nit > 0) {
            int icur = wave;
            int tcur = slist[icur];
            double bcur = bf[(size_t)tcur * 64 + lane];
            for (int j = 0; j < nit; ++j) {
                int inext = icur + VSPLIT;
                int tnext = (j + 1 < nit) ? (int)slist[inext] : NT;
                double bnext = bf[(size_t)tnext * 64 + lane];   // sentinel-safe prefetch
                PROCESS(tcur, bcur);
                icur = inext; tcur = tnext; bcur = bnext;
            }
        }
    }

    publish();
    __syncthreads();

    if (wave != 0) return;

    double best = smin2[0][lane];
    #pragma unroll
    for (int w = 1; w < VSPLIT; ++w) best = fmin(best, smin2[w][lane]);
    const int bpos = (int)(__double_as_longlong(best) & 0x1FFFULL);  // sorted pos
    const int bi = vord[bpos];
    const int oi = pord[pbase + lane];
    epilogue(oi, bi, xyz, rot, sw, bt, out);
#undef PROCESS
}

extern "C" void kernel_launch(void* const* d_in, const int* in_sizes, int n_in,
                              void* d_out, int out_size, void* d_ws, size_t ws_size,
                              hipStream_t stream) {
    const float* xyz   = (const float*)d_in[0];
    const float* rot   = (const float*)d_in[1];
    const float* verts = (const float*)d_in[2];
    const float* sw    = (const float*)d_in[3];
    const float* bt    = (const float*)d_in[4];
    float* out = (float*)d_out;

    // workspace layout
    double*   bfrag  = (double*)d_ws;                       // NTA*64 doubles
    float4*   tbb    = (float4*)(bfrag + NTA * 64);         // NTA float4
    int*      pord   = (int*)(tbb + NTA);                   // NPTS
    int*      vord   = pord + NPTS;                         // 6912
    unsigned* prank  = (unsigned*)(vord + 6912);            // NPTS
    unsigned* vrank  = prank + NPTS;                        // 6912
    unsigned* pbins  = vrank + 6912;                        // NBINS
    unsigned* vbins  = pbins + NBINS;                       // NBINS
    unsigned* pstart = vbins + NBINS;                       // NBINS+1 (+pad)
    unsigned* vstart = pstart + NBINS + 4;                  // NBINS+1

    hipMemsetAsync(pbins, 0, 2 * NBINS * sizeof(unsigned), stream);  // pbins+vbins

    hist2_k<<<(NPTS + NV + 255) / 256, 256, 0, stream>>>(xyz, verts, pbins, prank, vbins, vrank);
    prefix_k<<<1, 1024, 0, stream>>>(pbins, vbins, pstart, vstart);
    scatter2_k<<<(NPTS + NV + 255) / 256, 256, 0, stream>>>(xyz, verts, pstart, prank,
                                                            vstart, vrank, pord, vord);
    prep_frags_k<<<(NTA * 64) / 256, 256, 0, stream>>>(verts, vord, bfrag);
    tilebb_k<<<(NTA + 63) / 64, 64, 0, stream>>>(verts, vord, tbb);

    smplnn_scan<<<NBLK, 512, 0, stream>>>(xyz, rot, bfrag, sw, bt,
                                          pord, vord, tbb, vstart, out);
}

// Round 18
// 119.136 us; speedup vs baseline: 1.4136x; 1.1344x over previous
//
#include <hip/hip_runtime.h>
#include <math.h>

#define NPTS 65536
#define NV 6890
#define NT 432               // vertex tiles of 16 (432*16 = 6912 >= 6890)
#define NTA 440              // allocated tiles (sentinel-padded for prefetch)
#define NJ 24
#define NBINS 4096           // 12-bit Morton bins
#define VSPLIT 8             // waves per block
#define WIN 16               // phase-1 window tiles (2 per wave)
#define PTS_PER_BLK 64
#define NBLK (NPTS / PTS_PER_BLK)   // 1024

typedef double f64x4 __attribute__((ext_vector_type(4)));

// ---------- Morton (4 bits/axis, cell = 0.5 over [-4,4]) ----------
__device__ __forceinline__ unsigned mspread(unsigned v) {
    return (v & 1u) | ((v & 2u) << 2) | ((v & 4u) << 4) | ((v & 8u) << 6);
}
__device__ __forceinline__ unsigned morton12(float x, float y, float z) {
    int qx = (int)floorf((x + 4.0f) * 2.0f); qx = qx < 0 ? 0 : (qx > 15 ? 15 : qx);
    int qy = (int)floorf((y + 4.0f) * 2.0f); qy = qy < 0 ? 0 : (qy > 15 ? 15 : qy);
    int qz = (int)floorf((z + 4.0f) * 2.0f); qz = qz < 0 ? 0 : (qz > 15 ? 15 : qz);
    return mspread((unsigned)qx) | (mspread((unsigned)qy) << 1) | (mspread((unsigned)qz) << 2);
}

// ---------- fused binning kernels (order affects speed only, never values) ----------
__global__ void hist2_k(const float* __restrict__ xyz, const float* __restrict__ verts,
                        unsigned* __restrict__ pbins, unsigned* __restrict__ prank,
                        unsigned* __restrict__ vbins, unsigned* __restrict__ vrank) {
    int i = blockIdx.x * blockDim.x + threadIdx.x;
    if (i < NPTS) {
        unsigned c = morton12(xyz[3 * i], xyz[3 * i + 1], xyz[3 * i + 2]);
        prank[i] = atomicAdd(&pbins[c], 1u);
    } else {
        int j = i - NPTS;
        if (j < NV) {
            unsigned c = morton12(verts[3 * j], verts[3 * j + 1], verts[3 * j + 2]);
            vrank[j] = atomicAdd(&vbins[c], 1u);
        }
    }
}

__global__ void prefix_k(const unsigned* __restrict__ pb, const unsigned* __restrict__ vb,
                         unsigned* __restrict__ ps, unsigned* __restrict__ vs) {
    __shared__ unsigned s[NBINS];
    const int tid = threadIdx.x;                 // 1024 threads
    for (int pass = 0; pass < 2; ++pass) {
        const unsigned* in = pass ? vb : pb;
        unsigned* outp = pass ? vs : ps;
        for (int j = tid; j < NBINS; j += 1024) s[j] = in[j];
        __syncthreads();
        for (int off = 1; off < NBINS; off <<= 1) {
            unsigned v[4];
            #pragma unroll
            for (int q = 0; q < 4; ++q) {
                int j = tid + q * 1024;
                v[q] = (j >= off) ? s[j - off] : 0u;
            }
            __syncthreads();
            #pragma unroll
            for (int q = 0; q < 4; ++q) s[tid + q * 1024] += v[q];
            __syncthreads();
        }
        for (int j = tid; j < NBINS; j += 1024) outp[j + 1] = s[j];  // exclusive
        if (tid == 0) outp[0] = 0;
        __syncthreads();
    }
}

__global__ void scatter2_k(const float* __restrict__ xyz, const float* __restrict__ verts,
                           const unsigned* __restrict__ pstart, const unsigned* __restrict__ prank,
                           const unsigned* __restrict__ vstart, const unsigned* __restrict__ vrank,
                           int* __restrict__ pord, int* __restrict__ vord) {
    int i = blockIdx.x * blockDim.x + threadIdx.x;
    if (i < NPTS) {
        unsigned c = morton12(xyz[3 * i], xyz[3 * i + 1], xyz[3 * i + 2]);
        pord[pstart[c] + prank[i]] = i;
    } else {
        int j = i - NPTS;
        if (j < NV) {
            unsigned c = morton12(verts[3 * j], verts[3 * j + 1], verts[3 * j + 2]);
            vord[vstart[c] + vrank[j]] = j;
        }
    }
}

// ---------- B-fragment stream + tile spheres (fused; both r12-proven forms) ----------
__global__ void prep_frags_k(const float* __restrict__ verts, const int* __restrict__ vord,
                             double* __restrict__ bf, float4* __restrict__ tbb) {
    int e = blockIdx.x * blockDim.x + threadIdx.x;
    if (e < NTA * 64) {
        int l = e & 63;
        int t = e >> 6;
        int pos = t * 16 + (l & 15);
        int k = l >> 4;
        double val;
        if (pos < NV) {
            int j = vord[pos];
            if (k < 3) {
                val = (double)verts[3 * j + k];
            } else {
                double x = (double)verts[3 * j + 0];
                double y = (double)verts[3 * j + 1];
                double z = (double)verts[3 * j + 2];
                val = x * x + y * y + z * z;
            }
        } else {
            val = (k == 3) ? 1e300 : 0.0;
        }
        bf[e] = val;
    }
    // scalar bounding-sphere pass (r12-proven), one thread per tile
    if (e < NTA) {
        int t = e;
        if (t * 16 >= NV) { tbb[t] = make_float4(1e30f, 1e30f, 1e30f, 0.0f); return; }
        float mnx = 1e30f, mny = 1e30f, mnz = 1e30f;
        float mxx = -1e30f, mxy = -1e30f, mxz = -1e30f;
        for (int c = 0; c < 16; ++c) {
            int pos = t * 16 + c;
            if (pos >= NV) break;
            int j = vord[pos];
            float x = verts[3 * j], y = verts[3 * j + 1], z = verts[3 * j + 2];
            mnx = fminf(mnx, x); mxx = fmaxf(mxx, x);
            mny = fminf(mny, y); mxy = fmaxf(mxy, y);
            mnz = fminf(mnz, z); mxz = fmaxf(mxz, z);
        }
        float cx = (mnx + mxx) * 0.5f, cy = (mny + mxy) * 0.5f, cz = (mnz + mxz) * 0.5f;
        float r2 = 0.0f;
        for (int c = 0; c < 16; ++c) {
            int pos = t * 16 + c;
            if (pos >= NV) break;
            int j = vord[pos];
            float dx = verts[3 * j] - cx, dy = verts[3 * j + 1] - cy, dz = verts[3 * j + 2] - cz;
            r2 = fmaxf(r2, dx * dx + dy * dy + dz * dz);
        }
        float r = sqrtf(r2) * 1.0002f + 1e-5f;   // conservative inflation
        tbb[t] = make_float4(cx, cy, cz, r);
    }
}

// m = min(m, d with low-13 mantissa bits replaced by orv). Perturbation
// <= 2^13 ulp (~1e-12 rel) << NN gap (~1e-3): ordering-safe (rounds 6-17).
__device__ __forceinline__ void packmin(double& m, double d, unsigned orv) {
    unsigned long long u = __double_as_longlong(d);
    u = (u & ~0x1FFFULL) | (unsigned long long)orv;
    double t = __longlong_as_double(u);
    asm("v_min_f64 %0, %0, %1" : "+v"(m) : "v"(t));
}

// ---------- epilogue ----------
__device__ __forceinline__ void epilogue(int i, int bi,
                                         const float* __restrict__ xyz,
                                         const float* __restrict__ rot,
                                         const float* __restrict__ sw,
                                         const float* __restrict__ bt,
                                         float* __restrict__ out) {
    const float xf = xyz[3 * i + 0];
    const float yf = xyz[3 * i + 1];
    const float zf = xyz[3 * i + 2];

    const float* W = &sw[bi * NJ];
    float Tm[16];
    #pragma unroll
    for (int q = 0; q < 16; ++q) Tm[q] = 0.0f;
    #pragma unroll
    for (int kk = 0; kk < NJ; ++kk) {
        float w = W[kk];
        #pragma unroll
        for (int q = 0; q < 16; ++q) Tm[q] = fmaf(w, bt[16 * kk + q], Tm[q]);
    }

    float xb0 = Tm[0] * xf + Tm[1] * yf + Tm[2]  * zf + Tm[3];
    float xb1 = Tm[4] * xf + Tm[5] * yf + Tm[6]  * zf + Tm[7];
    float xb2 = Tm[8] * xf + Tm[9] * yf + Tm[10] * zf + Tm[11];

    float qr = rot[4 * i + 0];
    float qx = rot[4 * i + 1];
    float qy = rot[4 * i + 2];
    float qz = rot[4 * i + 3];
    float inv = 1.0f / sqrtf(qr * qr + qx * qx + qy * qy + qz * qz);
    qr *= inv; qx *= inv; qy *= inv; qz *= inv;

    float Rh[9];
    Rh[0] = 1.0f - 2.0f * (qy * qy + qz * qz);
    Rh[1] = 2.0f * (qx * qy - qr * qz);
    Rh[2] = 2.0f * (qx * qz + qr * qy);
    Rh[3] = 2.0f * (qx * qy + qr * qz);
    Rh[4] = 1.0f - 2.0f * (qx * qx + qz * qz);
    Rh[5] = 2.0f * (qy * qz - qr * qx);
    Rh[6] = 2.0f * (qx * qz - qr * qy);
    Rh[7] = 2.0f * (qy * qz + qr * qx);
    Rh[8] = 1.0f - 2.0f * (qx * qx + qy * qy);

    float RB[9];
    #pragma unroll
    for (int rr2 = 0; rr2 < 3; ++rr2) {
        #pragma unroll
        for (int cc = 0; cc < 3; ++cc) {
            RB[3 * rr2 + cc] = Tm[4 * rr2 + 0] * Rh[cc]
                             + Tm[4 * rr2 + 1] * Rh[3 + cc]
                             + Tm[4 * rr2 + 2] * Rh[6 + cc];
        }
    }

    out[3 * i + 0] = xb0;
    out[3 * i + 1] = xb1;
    out[3 * i + 2] = xb2;
    float* ob = out + 3 * NPTS + 9 * i;
    #pragma unroll
    for (int q = 0; q < 9; ++q) ob[q] = RB[q];
    float* ot = out + 12 * NPTS + 16 * i;
    #pragma unroll
    for (int q = 0; q < 16; ++q) ot[q] = Tm[q];
}

// ---------- main scan: phase-1 seed + per-point kept-tile list + dense list loop ----------
__launch_bounds__(512)
__global__ void smplnn_scan(const float* __restrict__ xyz,
                            const float* __restrict__ rot,
                            const double* __restrict__ bf,
                            const float* __restrict__ sw,
                            const float* __restrict__ bt,
                            const int* __restrict__ pord,
                            const int* __restrict__ vord,
                            const float4* __restrict__ tbb,
                            const unsigned* __restrict__ vstart,
                            float* __restrict__ out) {
    __shared__ float4 stbb[NTA];
    __shared__ double smin2[VSPLIT][PTS_PER_BLK];
    __shared__ float4 spts[PTS_PER_BLK];   // per-point (x,y,z,sU_p)
    __shared__ unsigned short slist[448];
    __shared__ int scount;

    const int tid  = threadIdx.x;
    const int lane = tid & 63;
    const int wave = tid >> 6;
    const int r = lane & 15;
    const int k = lane >> 4;
    const int pbase = blockIdx.x * PTS_PER_BLK;

    // cache all tile spheres in LDS (consumed after the first barrier)
    for (int j = tid; j < NTA; j += 512) stbb[j] = tbb[j];
    if (tid == 0) scount = 0;

    // A fragments via point indirection (sorted order -> original ids)
    const int o0 = pord[pbase + r];
    const int o1 = pord[pbase + 16 + r];
    const int o2 = pord[pbase + 32 + r];
    const int o3 = pord[pbase + 48 + r];
    double a0 = (k == 3) ? 1.0 : -2.0 * (double)xyz[3 * o0 + k];
    double a1 = (k == 3) ? 1.0 : -2.0 * (double)xyz[3 * o1 + k];
    double a2 = (k == 3) ? 1.0 : -2.0 * (double)xyz[3 * o2 + k];
    double a3 = (k == 3) ? 1.0 : -2.0 * (double)xyz[3 * o3 + k];

    // own point (lane <-> block point) for centroid and ||p||^2
    const int om = pord[pbase + lane];
    const float px = xyz[3 * om], py = xyz[3 * om + 1], pz = xyz[3 * om + 2];
    const double pn = (double)px * px + (double)py * py + (double)pz * pz;

    // block bbox (wave-wide butterfly; used only for the Morton centroid)
    float bxmin = px, bxmax = px, bymin = py, bymax = py, bzmin = pz, bzmax = pz;
    #pragma unroll
    for (int s = 1; s < 64; s <<= 1) {
        bxmin = fminf(bxmin, __shfl_xor(bxmin, s));
        bxmax = fmaxf(bxmax, __shfl_xor(bxmax, s));
        bymin = fminf(bymin, __shfl_xor(bymin, s));
        bymax = fmaxf(bymax, __shfl_xor(bymax, s));
        bzmin = fminf(bzmin, __shfl_xor(bzmin, s));
        bzmax = fmaxf(bzmax, __shfl_xor(bzmax, s));
    }

    const f64x4 zero = {0.0, 0.0, 0.0, 0.0};

    // D-layout self-calibration (as rounds 4-17)
    double ar  = (k == 3) ? (double)r : 0.0;
    double one = (k == 3) ? 1.0 : 0.0;
    f64x4 drow = __builtin_amdgcn_mfma_f64_16x16x4f64(ar, one, zero, 0, 0, 0);
    f64x4 dcol = __builtin_amdgcn_mfma_f64_16x16x4f64(one, ar, zero, 0, 0, 0);
    int rowid[4];
    unsigned colb[4];
    #pragma unroll
    for (int v = 0; v < 4; ++v) { rowid[v] = (int)drow[v]; colb[v] = (unsigned)(int)dcol[v]; }

    double m0[4], m1[4], m2[4], m3[4];
    #pragma unroll
    for (int v = 0; v < 4; ++v) { m0[v] = 1e301; m1[v] = 1e301; m2[v] = 1e301; m3[v] = 1e301; }

#define PROCESS(T, B) do {                                                        \
        unsigned tb_ = ((unsigned)(T)) << 4;                                      \
        f64x4 d0 = __builtin_amdgcn_mfma_f64_16x16x4f64(a0, (B), zero, 0, 0, 0);  \
        f64x4 d1 = __builtin_amdgcn_mfma_f64_16x16x4f64(a1, (B), zero, 0, 0, 0);  \
        f64x4 d2 = __builtin_amdgcn_mfma_f64_16x16x4f64(a2, (B), zero, 0, 0, 0);  \
        f64x4 d3 = __builtin_amdgcn_mfma_f64_16x16x4f64(a3, (B), zero, 0, 0, 0);  \
        unsigned q0_ = tb_ | colb[0], q1_ = tb_ | colb[1];                        \
        unsigned q2_ = tb_ | colb[2], q3_ = tb_ | colb[3];                        \
        packmin(m0[0], d0[0], q0_); packmin(m0[1], d0[1], q1_);                   \
        packmin(m0[2], d0[2], q2_); packmin(m0[3], d0[3], q3_);                   \
        packmin(m1[0], d1[0], q0_); packmin(m1[1], d1[1], q1_);                   \
        packmin(m1[2], d1[2], q2_); packmin(m1[3], d1[3], q3_);                   \
        packmin(m2[0], d2[0], q0_); packmin(m2[1], d2[1], q1_);                   \
        packmin(m2[2], d2[2], q2_); packmin(m2[3], d2[3], q3_);                   \
        packmin(m3[0], d3[0], q0_); packmin(m3[1], d3[1], q1_);                   \
        packmin(m3[2], d3[2], q2_); packmin(m3[3], d3[3], q3_);                   \
    } while (0)

    // phase-1 window around the block's Morton position
    unsigned bc = morton12((bxmin + bxmax) * 0.5f, (bymin + bymax) * 0.5f,
                           (bzmin + bzmax) * 0.5f);
    int tw0 = ((int)vstart[bc] >> 4) - WIN / 2;
    if (tw0 < 0) tw0 = 0;
    if (tw0 > NT - WIN) tw0 = NT - WIN;
    tw0 = __builtin_amdgcn_readfirstlane(tw0);

    {
        int ta = tw0 + 2 * wave;
        double ba = bf[(size_t)ta * 64 + lane];
        double bb2 = bf[(size_t)(ta + 1) * 64 + lane];
        PROCESS(ta, ba);
        PROCESS(ta + 1, bb2);
    }

    auto publish = [&]() {
        double val = 0.0;
        #pragma unroll
        for (int f = 0; f < 4; ++f) {
            #pragma unroll
            for (int v = 0; v < 4; ++v) {
                double q = (f == 0) ? m0[v] : (f == 1) ? m1[v] : (f == 2) ? m2[v] : m3[v];
                #pragma unroll
                for (int s = 1; s < 16; s <<= 1) q = fmin(q, __shfl_xor(q, s, 16));
                if ((lane & 15) == f * 4 + v) val = q;
            }
        }
        smin2[wave][((lane & 15) >> 2) * 16 + rowid[lane & 3]] = val;
    };

    publish();
    __syncthreads();

    // per-point seed bound: sU_p = sqrt(best dist^2 so far), inflated.
    // (score = dist^2 - ||p||^2, so add pn back; +1e-4 abs slack >> f32 rounding)
    double bp_ = smin2[0][lane];
    #pragma unroll
    for (int w = 1; w < VSPLIT; ++w) bp_ = fmin(bp_, smin2[w][lane]);
    double d2p = bp_ + pn;
    if (d2p < 0.0) d2p = 0.0;
    const float sup = sqrtf((float)(d2p * 1.00001 + 1e-8)) + 1e-4f;
    if (wave == 0) spts[lane] = make_float4(px, py, pz, sup);
    __syncthreads();   // smin2 reuse; spts visible; scount zero visible

    // build kept-tile list: one thread per tile, testing all 64 points (LDS broadcast)
    if (tid < NT) {
        const int t = tid;
        float4 s0 = stbb[t];
        const float rt = s0.w;
        const float r2t = rt * rt;
        float acc = 1.0f;
        #pragma unroll 4
        for (int p = 0; p < PTS_PER_BLK; ++p) {
            float4 q = spts[p];
            float dx = q.x - s0.x, dy = q.y - s0.y, dz = q.z - s0.z;
            float dist2 = fmaf(dx, dx, fmaf(dy, dy, dz * dz));
            float rhs = fmaf(2.0f * rt, q.w, fmaf(q.w, q.w, r2t));  // (rt+sU_p)^2
            acc = fminf(acc, dist2 - rhs);
        }
        bool keep = (acc <= 0.0f) && (t < tw0 || t >= tw0 + WIN);
        if (keep) {
            int p2 = atomicAdd(&scount, 1);
            slist[p2] = (unsigned short)t;
        }
    }
    __syncthreads();

    const int M = scount;
    const int Mp = (M + VSPLIT - 1) & ~(VSPLIT - 1);
    if (tid >= M && tid < Mp) slist[tid] = NT;   // sentinel tile (harmless no-op)
    __syncthreads();

    // dense pipelined loop over kept tiles (strided across waves; order-free min)
    {
        const int nit = Mp / VSPLIT;
        if (nit > 0) {
            int icur = wave;
            int tcur = slist[icur];
            double bcur = bf[(size_t)tcur * 64 + lane];
            for (int j = 0; j < nit; ++j) {
                int inext = icur + VSPLIT;
                int tnext = (j + 1 < nit) ? (int)slist[inext] : NT;
                double bnext = bf[(size_t)tnext * 64 + lane];   // sentinel-safe prefetch
                PROCESS(tcur, bcur);
                icur = inext; tcur = tnext; bcur = bnext;
            }
        }
    }

    publish();
    __syncthreads();

    if (wave != 0) return;

    double best = smin2[0][lane];
    #pragma unroll
    for (int w = 1; w < VSPLIT; ++w) best = fmin(best, smin2[w][lane]);
    const int bpos = (int)(__double_as_longlong(best) & 0x1FFFULL);  // sorted pos
    const int bi = vord[bpos];
    const int oi = pord[pbase + lane];
    epilogue(oi, bi, xyz, rot, sw, bt, out);
#undef PROCESS
}

extern "C" void kernel_launch(void* const* d_in, const int* in_sizes, int n_in,
                              void* d_out, int out_size, void* d_ws, size_t ws_size,
                              hipStream_t stream) {
    const float* xyz   = (const float*)d_in[0];
    const float* rot   = (const float*)d_in[1];
    const float* verts = (const float*)d_in[2];
    const float* sw    = (const float*)d_in[3];
    const float* bt    = (const float*)d_in[4];
    float* out = (float*)d_out;

    // workspace layout
    double*   bfrag  = (double*)d_ws;                       // NTA*64 doubles
    float4*   tbb    = (float4*)(bfrag + NTA * 64);         // NTA float4
    int*      pord   = (int*)(tbb + NTA);                   // NPTS
    int*      vord   = pord + NPTS;                         // 6912
    unsigned* prank  = (unsigned*)(vord + 6912);            // NPTS
    unsigned* vrank  = prank + NPTS;                        // 6912
    unsigned* pbins  = vrank + 6912;                        // NBINS
    unsigned* vbins  = pbins + NBINS;                       // NBINS
    unsigned* pstart = vbins + NBINS;                       // NBINS+1 (+pad)
    unsigned* vstart = pstart + NBINS + 4;                  // NBINS+1

    hipMemsetAsync(pbins, 0, 2 * NBINS * sizeof(unsigned), stream);  // pbins+vbins

    hist2_k<<<(NPTS + NV + 255) / 256, 256, 0, stream>>>(xyz, verts, pbins, prank, vbins, vrank);
    prefix_k<<<1, 1024, 0, stream>>>(pbins, vbins, pstart, vstart);
    scatter2_k<<<(NPTS + NV + 255) / 256, 256, 0, stream>>>(xyz, verts, pstart, prank,
                                                            vstart, vrank, pord, vord);
    prep_frags_k<<<(NTA * 64 + 255) / 256, 256, 0, stream>>>(verts, vord, bfrag, tbb);

    smplnn_scan<<<NBLK, 512, 0, stream>>>(xyz, rot, bfrag, sw, bt,
                                          pord, vord, tbb, vstart, out);
}